// Round 1
// baseline (205902.710 us; speedup 1.0000x reference)
//
#include <hip/hip_runtime.h>

typedef _Float16 f16;
typedef _Float16 f16x8 __attribute__((ext_vector_type(8)));
typedef float f32x4 __attribute__((ext_vector_type(4)));

#define DE 4
#define BS 64
#define SL 256
#define FL 256
#define SI 512
#define SH 512

__device__ __forceinline__ float sigmoidf_(float x) { return 1.f / (1.f + __expf(-x)); }
// overflow-safe tanh: for e=inf -> 1, e=0 -> -1
__device__ __forceinline__ float tanhf_(float x) { float e = __expf(2.f * x); return 1.f - 2.f / (e + 1.f); }

// Weights: out[cell][n][k] (n in [0,2048), k in [0,1024)); k<512 from W[cell][k][n], else V[cell][k-512][n]
__global__ void conv_w(const float* __restrict__ W, const float* __restrict__ V,
                       f16* __restrict__ out) {
  long idx = (long)blockIdx.x * blockDim.x + threadIdx.x;  // total 16*2048*1024
  int k = (int)(idx & 1023);
  int n = (int)((idx >> 10) & 2047);
  long cell = idx >> 21;
  float v = (k < 512) ? W[(cell * 512 + k) * 2048 + n]
                      : V[(cell * 512 + (k - 512)) * 2048 + n];
  out[idx] = (f16)v;
}

// xt[t][b][i] = x[b][t][i]  (fp32 -> fp16, transpose to per-timestep contiguous)
__global__ void conv_x(const float* __restrict__ x, f16* __restrict__ xt) {
  long idx = (long)blockIdx.x * blockDim.x + threadIdx.x;  // total 256*64*512
  int i = (int)(idx & 511);
  int b = (int)((idx >> 9) & 63);
  int t = (int)(idx >> 15);
  xt[idx] = (f16)x[((long)b * SL + t) * SI + i];
}

// fint[n][k] = fin_W[k][n]
__global__ void conv_fin(const float* __restrict__ finW, f16* __restrict__ fint) {
  long idx = (long)blockIdx.x * blockDim.x + threadIdx.x;  // total 512*512
  int k = (int)(idx & 511);
  int n = (int)(idx >> 9);
  fint[idx] = (f16)finW[(long)k * SI + n];
}

// h (fp16) and c (fp32) initial state into ping-pong buffer 0
__global__ void init_state(const float* __restrict__ h0, const float* __restrict__ c0,
                           f16* __restrict__ h16, float* __restrict__ c32) {
  long idx = (long)blockIdx.x * blockDim.x + threadIdx.x;  // total 4*64*512
  h16[idx] = (f16)h0[idx];
  c32[idx] = c0[idx];
}

// One LSTM cell: z = [inp,h] @ Wt^T + b ; gates [f,i,g,o]; H,C update.
// 32 blocks x 64 threads: each wave computes 16 H-columns (n0..n0+15) for all 64 rows, all 4 gates.
__global__ __launch_bounds__(64) void lstm_cell(
    const f16* __restrict__ inp, const f16* __restrict__ hin,
    const float* __restrict__ cin, f16* __restrict__ hout, float* __restrict__ cout,
    const f16* __restrict__ wt,   // [2048][1024] fp16, row n = [W[:,n] ; V[:,n]]
    const float* __restrict__ bias,  // [2048]
    f16* __restrict__ ys, int ysj) {
  const int lane = threadIdx.x;
  const int col = lane & 15;
  const int kg = lane >> 4;
  const int n0 = blockIdx.x * 16;
  const int koff = kg * 8;

  f32x4 acc[4][4];
#pragma unroll
  for (int g = 0; g < 4; ++g)
#pragma unroll
    for (int mi = 0; mi < 4; ++mi)
      acc[g][mi] = 0.f;

#pragma unroll 2
  for (int kk = 0; kk < 32; ++kk) {
    const f16* asrc = (kk < 16) ? (inp + kk * 32 + koff) : (hin + (kk - 16) * 32 + koff);
    f16x8 a[4];
#pragma unroll
    for (int mi = 0; mi < 4; ++mi)
      a[mi] = *(const f16x8*)(asrc + (mi * 16 + col) * SH);
#pragma unroll
    for (int g = 0; g < 4; ++g) {
      f16x8 b = *(const f16x8*)(wt + (long)(g * 512 + n0 + col) * 1024 + kk * 32 + koff);
#pragma unroll
      for (int mi = 0; mi < 4; ++mi)
        acc[g][mi] = __builtin_amdgcn_mfma_f32_16x16x32_f16(a[mi], b, acc[g][mi], 0, 0, 0);
    }
  }

  const int n = n0 + col;
  const float bf = bias[n];
  const float bi = bias[512 + n];
  const float bg = bias[1024 + n];
  const float bo = bias[1536 + n];
#pragma unroll
  for (int mi = 0; mi < 4; ++mi) {
#pragma unroll
    for (int r = 0; r < 4; ++r) {
      int row = mi * 16 + kg * 4 + r;
      float zf = acc[0][mi][r] + bf;
      float zi = acc[1][mi][r] + bi;
      float zg = acc[2][mi][r] + bg;
      float zo = acc[3][mi][r] + bo;
      float f = sigmoidf_(zf);
      float i = sigmoidf_(zi);
      float g = tanhf_(zg);
      float o = sigmoidf_(zo);
      float c = f * cin[row * SH + n] + i * g;
      float h = o * tanhf_(c);
      cout[row * SH + n] = c;
      hout[row * SH + n] = (f16)h;
      if (ysj >= 0) ys[((long)row * (FL * 4) + ysj) * SH + n] = (f16)h;
    }
  }
}

// out[m][n] = sigmoid( ys[m][:] @ fint[n][:] + fin_b[n] ), m in [0,65536), n in [0,512)
__global__ __launch_bounds__(256) void final_gemm(const f16* __restrict__ ys,
                                                  const f16* __restrict__ fint,
                                                  const float* __restrict__ finb,
                                                  float* __restrict__ out) {
  const int lane = threadIdx.x & 63;
  const int w = threadIdx.x >> 6;
  const int col = lane & 15;
  const int kg = lane >> 4;
  const long m0 = (long)blockIdx.y * 64;
  const int n0 = (blockIdx.x * 4 + w) * 16;

  f32x4 acc[4];
#pragma unroll
  for (int mi = 0; mi < 4; ++mi) acc[mi] = 0.f;

#pragma unroll 2
  for (int kk = 0; kk < 16; ++kk) {
    f16x8 b = *(const f16x8*)(fint + (long)(n0 + col) * 512 + kk * 32 + kg * 8);
#pragma unroll
    for (int mi = 0; mi < 4; ++mi) {
      f16x8 a = *(const f16x8*)(ys + (m0 + mi * 16 + col) * 512 + kk * 32 + kg * 8);
      acc[mi] = __builtin_amdgcn_mfma_f32_16x16x32_f16(a, b, acc[mi], 0, 0, 0);
    }
  }
  const int n = n0 + col;
  const float bn = finb[n];
#pragma unroll
  for (int mi = 0; mi < 4; ++mi)
#pragma unroll
    for (int r = 0; r < 4; ++r)
      out[(m0 + mi * 16 + kg * 4 + r) * 512 + n] = sigmoidf_(acc[mi][r] + bn);
}

extern "C" void kernel_launch(void* const* d_in, const int* in_sizes, int n_in,
                              void* d_out, int out_size, void* d_ws, size_t ws_size,
                              hipStream_t stream) {
  const float* x      = (const float*)d_in[0];
  // d_in[1] = fl (scalar, known 256 at compile time)
  const float* enc_W  = (const float*)d_in[2];
  const float* enc_V  = (const float*)d_in[3];
  const float* enc_b  = (const float*)d_in[4];
  const float* enc_h0 = (const float*)d_in[5];
  const float* enc_c0 = (const float*)d_in[6];
  const float* dec_W  = (const float*)d_in[7];
  const float* dec_V  = (const float*)d_in[8];
  const float* dec_b  = (const float*)d_in[9];
  const float* dec_h0 = (const float*)d_in[10];
  const float* dec_c0 = (const float*)d_in[11];
  const float* fin_W  = (const float*)d_in[12];
  const float* fin_b  = (const float*)d_in[13];
  float* out = (float*)d_out;

  // workspace layout (~222 MB)
  f16* wt_enc = (f16*)d_ws;                                   // 16*2048*1024
  f16* wt_dec = wt_enc + (long)16 * 2048 * 1024;              // 16*2048*1024
  f16* xt     = wt_dec + (long)16 * 2048 * 1024;              // 256*64*512
  f16* fint   = xt + (long)SL * BS * SI;                      // 512*512
  f16* ys     = fint + (long)SH * SI;                         // 64*1024*512
  f16* h_enc  = ys + (long)BS * (FL * 4) * SH;                // 2*4*64*512
  f16* h_dec  = h_enc + (long)2 * 4 * BS * SH;                // 2*4*64*512
  float* c_enc = (float*)(h_dec + (long)2 * 4 * BS * SH);     // 2*4*64*512 f32
  float* c_dec = c_enc + (long)2 * 4 * BS * SH;               // 2*4*64*512 f32

  conv_w<<<131072, 256, 0, stream>>>(enc_W, enc_V, wt_enc);
  conv_w<<<131072, 256, 0, stream>>>(dec_W, dec_V, wt_dec);
  conv_x<<<32768, 256, 0, stream>>>(x, xt);
  conv_fin<<<1024, 256, 0, stream>>>(fin_W, fint);
  init_state<<<512, 256, 0, stream>>>(enc_h0, enc_c0, h_enc, c_enc);
  init_state<<<512, 256, 0, stream>>>(dec_h0, dec_c0, h_dec, c_dec);

  const long HSz = (long)BS * SH;  // 32768 elements per (e) state slab

  // -------- encoder: 256 t x 4 L x 4 e sequential cells --------
  for (int t = 0; t < SL; ++t) {
    for (int L = 0; L < 4; ++L) {
      int v = t * 4 + L, p = v & 1;
      for (int e = 0; e < 4; ++e) {
        const f16* inp = (e == 0) ? (xt + (long)t * HSz)
                                  : (h_enc + ((1 - p) * 4 + (e - 1)) * HSz);
        lstm_cell<<<32, 64, 0, stream>>>(
            inp,
            h_enc + (p * 4 + e) * HSz, c_enc + (p * 4 + e) * HSz,
            h_enc + ((1 - p) * 4 + e) * HSz, c_enc + ((1 - p) * 4 + e) * HSz,
            wt_enc + (long)(L * 4 + e) * 2048 * 1024, enc_b + (L * 4 + e) * 2048,
            (f16*)nullptr, -1);
      }
    }
  }
  // encoder final state (state0) lives in h_enc buffer 0, slot e=3
  // (last visit v=1023 wrote buffer 1-(1023&1)=0)

  // -------- decoder: 256 t x 4 L x 4 e sequential cells --------
  for (int t = 0; t < FL; ++t) {
    for (int L = 0; L < 4; ++L) {
      int v = t * 4 + L, p = v & 1;
      for (int e = 0; e < 4; ++e) {
        const f16* inp;
        if (e == 0)
          inp = (v == 0) ? (h_enc + (0 * 4 + 3) * HSz)   // state0
                         : (h_dec + (p * 4 + 3) * HSz);  // state from previous list
        else
          inp = h_dec + ((1 - p) * 4 + (e - 1)) * HSz;
        int ysj = (e == 3) ? (t * 4 + L) : -1;
        lstm_cell<<<32, 64, 0, stream>>>(
            inp,
            h_dec + (p * 4 + e) * HSz, c_dec + (p * 4 + e) * HSz,
            h_dec + ((1 - p) * 4 + e) * HSz, c_dec + ((1 - p) * 4 + e) * HSz,
            wt_dec + (long)(L * 4 + e) * 2048 * 1024, dec_b + (L * 4 + e) * 2048,
            ys, ysj);
      }
    }
  }

  // -------- final projection + sigmoid --------
  dim3 fg(8, 1024);
  final_gemm<<<fg, 256, 0, stream>>>(ys, fint, fin_b, out);
}

// Round 2
// 172719.409 us; speedup vs baseline: 1.1921x; 1.1921x over previous
//
#include <hip/hip_runtime.h>

typedef _Float16 f16;
typedef _Float16 f16x8 __attribute__((ext_vector_type(8)));
typedef float f32x4 __attribute__((ext_vector_type(4)));

#define BS 64
#define SL 256
#define FL 256
#define SI 512
#define SH 512
#define NB 32
#define NSTEP 8192

__device__ __forceinline__ float sigmoidf_(float x) { return 1.f / (1.f + __expf(-x)); }
__device__ __forceinline__ float tanhf_(float x) { float e = __expf(2.f * x); return 1.f - 2.f / (e + 1.f); }

// Weights: out[cell][n][k] (n in [0,2048), k in [0,1024)); k<512 from W[cell][k][n], else V[cell][k-512][n]
__global__ void conv_w(const float* __restrict__ W, const float* __restrict__ V,
                       f16* __restrict__ out) {
  long idx = (long)blockIdx.x * blockDim.x + threadIdx.x;  // total 16*2048*1024
  int k = (int)(idx & 1023);
  int n = (int)((idx >> 10) & 2047);
  long cell = idx >> 21;
  float v = (k < 512) ? W[(cell * 512 + k) * 2048 + n]
                      : V[(cell * 512 + (k - 512)) * 2048 + n];
  out[idx] = (f16)v;
}

// xt[t][b][i] = x[b][t][i]
__global__ void conv_x(const float* __restrict__ x, f16* __restrict__ xt) {
  long idx = (long)blockIdx.x * blockDim.x + threadIdx.x;  // total 256*64*512
  int i = (int)(idx & 511);
  int b = (int)((idx >> 9) & 63);
  int t = (int)(idx >> 15);
  xt[idx] = (f16)x[((long)b * SL + t) * SI + i];
}

// fint[n][k] = fin_W[k][n]
__global__ void conv_fin(const float* __restrict__ finW, f16* __restrict__ fint) {
  long idx = (long)blockIdx.x * blockDim.x + threadIdx.x;  // total 512*512
  int k = (int)(idx & 511);
  int n = (int)(idx >> 9);
  fint[idx] = (f16)finW[(long)k * SI + n];
}

// h (fp16, ping-pong buffer 0) and c (fp32, single buffer) initial state
__global__ void init_state(const float* __restrict__ h0, const float* __restrict__ c0,
                           f16* __restrict__ h16, float* __restrict__ c32) {
  long idx = (long)blockIdx.x * blockDim.x + threadIdx.x;  // total 4*64*512
  h16[idx] = (f16)h0[idx];
  c32[idx] = c0[idx];
}

// Persistent kernel: all 8192 LSTM cells, one device-wide barrier per cell.
// 32 blocks x 1024 threads. Block owns 16 hidden cols (all 4 gates).
// Wave wid = q*4+g: gate g, K-quarter q (K=256 slice). 32 MFMAs/wave/cell.
__global__ __launch_bounds__(1024) void lstm_persist(
    const f16* __restrict__ xt,
    const f16* __restrict__ wt_enc, const f16* __restrict__ wt_dec,
    const float* __restrict__ enc_b, const float* __restrict__ dec_b,
    f16* __restrict__ h_enc, f16* __restrict__ h_dec,
    float* __restrict__ c_enc, float* __restrict__ c_dec,
    f16* __restrict__ ys, int* __restrict__ ctr) {
  const int tid = threadIdx.x;
  const int lane = tid & 63;
  const int wid = tid >> 6;
  const int g = wid & 3;
  const int q = wid >> 2;
  const int col = lane & 15;
  const int kg = lane >> 4;
  const int n0 = blockIdx.x << 4;

  __shared__ float zred[16][64][17];  // padded: conflict-free write/read

  // this wave's weight element offset within a cell's [2048][1024] slab
  const long wofs = (long)(g * 512 + n0 + col) * 1024 + q * 256 + kg * 8;

  f16x8 B[8], Bn[8];

  // prefetch weights for step 0 (encoder cell 0)
  {
    const f16* w = wt_enc + wofs;
#pragma unroll
    for (int kk = 0; kk < 8; ++kk) Bn[kk] = *(const f16x8*)(w + kk * 32);
  }

  for (int s = 0; s < NSTEP; ++s) {
#pragma unroll
    for (int kk = 0; kk < 8; ++kk) B[kk] = Bn[kk];

    // ---- schedule decode (uniform scalar) ----
    const bool enc = s < 4096;
    const int sp = enc ? s : s - 4096;
    const int v = sp >> 2, e = sp & 3, L = v & 3, t = v >> 2, p = v & 1;
    const int HSz = BS * SH;
    const f16* inp;
    if (enc) {
      inp = (e == 0) ? (xt + (long)t * HSz)
                     : (h_enc + ((1 - p) * 4 + (e - 1)) * HSz);
    } else {
      if (e == 0)
        inp = (v == 0) ? (h_enc + 3 * HSz)            // state0: enc buf0 slot3
                       : (h_dec + (p * 4 + 3) * HSz); // prev list's state
      else
        inp = h_dec + ((1 - p) * 4 + (e - 1)) * HSz;
    }
    const f16* hin = (enc ? h_enc : h_dec) + (p * 4 + e) * HSz;
    f16* hout = (enc ? h_enc : h_dec) + ((1 - p) * 4 + e) * HSz;
    float* cs = (enc ? c_enc : c_dec) + e * HSz;
    const float* bias = (enc ? enc_b : dec_b) + (L * 4 + e) * 2048;
    const int ysj = (!enc && e == 3) ? (t * 4 + L) : -1;

    // A source for this wave: q=0,1 -> inp (k 0..511); q=2,3 -> hin (k 512..1023)
    const f16* asrc = ((q < 2) ? inp : hin) + (q & 1) * 256 + kg * 8;

    f32x4 acc[4];
#pragma unroll
    for (int mi = 0; mi < 4; ++mi) acc[mi] = 0.f;

#pragma unroll
    for (int kk = 0; kk < 8; ++kk) {
      const f16* ab = asrc + kk * 32;
      f16x8 a0 = *(const f16x8*)(ab + (0 * 16 + col) * SH);
      f16x8 a1 = *(const f16x8*)(ab + (1 * 16 + col) * SH);
      f16x8 a2 = *(const f16x8*)(ab + (2 * 16 + col) * SH);
      f16x8 a3 = *(const f16x8*)(ab + (3 * 16 + col) * SH);
      acc[0] = __builtin_amdgcn_mfma_f32_16x16x32_f16(a0, B[kk], acc[0], 0, 0, 0);
      acc[1] = __builtin_amdgcn_mfma_f32_16x16x32_f16(a1, B[kk], acc[1], 0, 0, 0);
      acc[2] = __builtin_amdgcn_mfma_f32_16x16x32_f16(a2, B[kk], acc[2], 0, 0, 0);
      acc[3] = __builtin_amdgcn_mfma_f32_16x16x32_f16(a3, B[kk], acc[3], 0, 0, 0);
    }

    // prefetch next step's weights (latency hides under LDS/gate/barrier phases)
    if (s + 1 < NSTEP) {
      const int s2 = s + 1;
      const int sp2 = (s2 < 4096) ? s2 : s2 - 4096;
      const int e2 = sp2 & 3, L2 = (sp2 >> 2) & 3;
      const f16* w = ((s2 < 4096) ? wt_enc : wt_dec) +
                     (long)(L2 * 4 + e2) * (2048 * 1024) + wofs;
#pragma unroll
      for (int kk = 0; kk < 8; ++kk) Bn[kk] = *(const f16x8*)(w + kk * 32);
    }

    // ---- cross-wave K reduction via LDS ----
#pragma unroll
    for (int mi = 0; mi < 4; ++mi)
#pragma unroll
      for (int r = 0; r < 4; ++r)
        zred[wid][mi * 16 + kg * 4 + r][col] = acc[mi][r];

    __syncthreads();

    // ---- gate phase: one (row, col) per thread ----
    {
      const int row = tid >> 4, ci = tid & 15, n = n0 + ci;
      float zf = bias[n], zi = bias[512 + n], zg = bias[1024 + n], zo = bias[1536 + n];
#pragma unroll
      for (int qq = 0; qq < 4; ++qq) {
        zf += zred[qq * 4 + 0][row][ci];
        zi += zred[qq * 4 + 1][row][ci];
        zg += zred[qq * 4 + 2][row][ci];
        zo += zred[qq * 4 + 3][row][ci];
      }
      float f = sigmoidf_(zf);
      float i = sigmoidf_(zi);
      float gg = tanhf_(zg);
      float o = sigmoidf_(zo);
      float cc = f * cs[row * SH + n] + i * gg;
      cs[row * SH + n] = cc;
      f16 h = (f16)(o * tanhf_(cc));
      hout[row * SH + n] = h;
      if (ysj >= 0) ys[((long)row * 1024 + ysj) * SH + n] = h;
    }

    // ---- device-wide barrier (leader-based, monotone counter) ----
    __syncthreads();  // drains all waves' stores (vmcnt) before leader signals
    if (tid == 0) {
      __threadfence();  // device-scope: push H to coherence point (wbL2)
      __hip_atomic_fetch_add(ctr, 1, __ATOMIC_RELEASE, __HIP_MEMORY_SCOPE_AGENT);
      const int target = (s + 1) * NB;
      while (__hip_atomic_load(ctr, __ATOMIC_ACQUIRE, __HIP_MEMORY_SCOPE_AGENT) < target)
        __builtin_amdgcn_s_sleep(2);
    }
    __syncthreads();
  }
}

// out[m][n] = sigmoid( ys[m][:] @ fint[n][:] + fin_b[n] )
__global__ __launch_bounds__(256) void final_gemm(const f16* __restrict__ ys,
                                                  const f16* __restrict__ fint,
                                                  const float* __restrict__ finb,
                                                  float* __restrict__ out) {
  const int lane = threadIdx.x & 63;
  const int w = threadIdx.x >> 6;
  const int col = lane & 15;
  const int kg = lane >> 4;
  const long m0 = (long)blockIdx.y * 64;
  const int n0 = (blockIdx.x * 4 + w) * 16;

  f32x4 acc[4];
#pragma unroll
  for (int mi = 0; mi < 4; ++mi) acc[mi] = 0.f;

#pragma unroll 2
  for (int kk = 0; kk < 16; ++kk) {
    f16x8 b = *(const f16x8*)(fint + (long)(n0 + col) * 512 + kk * 32 + kg * 8);
#pragma unroll
    for (int mi = 0; mi < 4; ++mi) {
      f16x8 a = *(const f16x8*)(ys + (m0 + mi * 16 + col) * 512 + kk * 32 + kg * 8);
      acc[mi] = __builtin_amdgcn_mfma_f32_16x16x32_f16(a, b, acc[mi], 0, 0, 0);
    }
  }
  const int n = n0 + col;
  const float bn = finb[n];
#pragma unroll
  for (int mi = 0; mi < 4; ++mi)
#pragma unroll
    for (int r = 0; r < 4; ++r)
      out[(m0 + mi * 16 + kg * 4 + r) * 512 + n] = sigmoidf_(acc[mi][r] + bn);
}

extern "C" void kernel_launch(void* const* d_in, const int* in_sizes, int n_in,
                              void* d_out, int out_size, void* d_ws, size_t ws_size,
                              hipStream_t stream) {
  const float* x      = (const float*)d_in[0];
  const float* enc_W  = (const float*)d_in[2];
  const float* enc_V  = (const float*)d_in[3];
  const float* enc_b  = (const float*)d_in[4];
  const float* enc_h0 = (const float*)d_in[5];
  const float* enc_c0 = (const float*)d_in[6];
  const float* dec_W  = (const float*)d_in[7];
  const float* dec_V  = (const float*)d_in[8];
  const float* dec_b  = (const float*)d_in[9];
  const float* dec_h0 = (const float*)d_in[10];
  const float* dec_c0 = (const float*)d_in[11];
  const float* fin_W  = (const float*)d_in[12];
  const float* fin_b  = (const float*)d_in[13];
  float* out = (float*)d_out;

  // workspace layout
  f16* wt_enc = (f16*)d_ws;                                   // 16*2048*1024
  f16* wt_dec = wt_enc + (long)16 * 2048 * 1024;              // 16*2048*1024
  f16* xt     = wt_dec + (long)16 * 2048 * 1024;              // 256*64*512
  f16* fint   = xt + (long)SL * BS * SI;                      // 512*512
  f16* ys     = fint + (long)SH * SI;                         // 64*1024*512
  f16* h_enc  = ys + (long)BS * (FL * 4) * SH;                // 2*4*64*512
  f16* h_dec  = h_enc + (long)2 * 4 * BS * SH;                // 2*4*64*512
  float* c_enc = (float*)(h_dec + (long)2 * 4 * BS * SH);     // 4*64*512 f32
  float* c_dec = c_enc + (long)4 * BS * SH;                   // 4*64*512 f32
  int* ctr = (int*)(c_dec + (long)4 * BS * SH);

  hipMemsetAsync(ctr, 0, 256, stream);

  conv_w<<<131072, 256, 0, stream>>>(enc_W, enc_V, wt_enc);
  conv_w<<<131072, 256, 0, stream>>>(dec_W, dec_V, wt_dec);
  conv_x<<<32768, 256, 0, stream>>>(x, xt);
  conv_fin<<<1024, 256, 0, stream>>>(fin_W, fint);
  init_state<<<512, 256, 0, stream>>>(enc_h0, enc_c0, h_enc, c_enc);
  init_state<<<512, 256, 0, stream>>>(dec_h0, dec_c0, h_dec, c_dec);

  lstm_persist<<<NB, 1024, 0, stream>>>(xt, wt_enc, wt_dec, enc_b, dec_b,
                                        h_enc, h_dec, c_enc, c_dec, ys, ctr);

  dim3 fg(8, 1024);
  final_gemm<<<fg, 256, 0, stream>>>(ys, fint, fin_b, out);
}

// Round 3
// 169143.726 us; speedup vs baseline: 1.2173x; 1.0211x over previous
//
#include <hip/hip_runtime.h>

typedef _Float16 f16;
typedef _Float16 f16x8 __attribute__((ext_vector_type(8)));
typedef float f32x4 __attribute__((ext_vector_type(4)));

#define BS 64
#define SL 256
#define FL 256
#define SI 512
#define SH 512
#define NB 32
#define NSTEP 8192

__device__ __forceinline__ float sigmoidf_(float x) { return 1.f / (1.f + __expf(-x)); }
__device__ __forceinline__ float tanhf_(float x) { float e = __expf(2.f * x); return 1.f - 2.f / (e + 1.f); }

// Pack weights in MFMA-fragment order:
// widx = (((((cell*32+nt)*4+g)*2+kh)*16+kk)*64 + lane)*8 + j
// maps to source n = g*512 + nt*16 + (lane&15), k = kh*512 + kk*32 + (lane>>4)*8 + j
// k<512 -> W[cell][k][n], else V[cell][k-512][n]. One wave-load = contiguous 1KB.
__global__ void conv_w(const float* __restrict__ W, const float* __restrict__ V,
                       f16* __restrict__ out) {
  long idx = (long)blockIdx.x * blockDim.x + threadIdx.x;  // total 16*2048*1024 = 2^25
  int j    = (int)(idx & 7);
  int lane = (int)((idx >> 3) & 63);
  int kk   = (int)((idx >> 9) & 15);
  int kh   = (int)((idx >> 13) & 1);
  int g    = (int)((idx >> 14) & 3);
  int nt   = (int)((idx >> 16) & 31);
  long cell = idx >> 21;
  int n = g * 512 + nt * 16 + (lane & 15);
  int k = kh * 512 + kk * 32 + (lane >> 4) * 8 + j;
  float v = (k < 512) ? W[(cell * 512 + k) * 2048 + n]
                      : V[(cell * 512 + (k - 512)) * 2048 + n];
  out[idx] = (f16)v;
}

// xt[t][b][i] = x[b][t][i]
__global__ void conv_x(const float* __restrict__ x, f16* __restrict__ xt) {
  long idx = (long)blockIdx.x * blockDim.x + threadIdx.x;  // total 256*64*512
  int i = (int)(idx & 511);
  int b = (int)((idx >> 9) & 63);
  int t = (int)(idx >> 15);
  xt[idx] = (f16)x[((long)b * SL + t) * SI + i];
}

// fint[n][k] = fin_W[k][n]
__global__ void conv_fin(const float* __restrict__ finW, f16* __restrict__ fint) {
  long idx = (long)blockIdx.x * blockDim.x + threadIdx.x;  // total 512*512
  int k = (int)(idx & 511);
  int n = (int)(idx >> 9);
  fint[idx] = (f16)finW[(long)k * SI + n];
}

// h (fp16, ping-pong buffer 0) and c (fp32, single buffer) initial state
__global__ void init_state(const float* __restrict__ h0, const float* __restrict__ c0,
                           f16* __restrict__ h16, float* __restrict__ c32) {
  long idx = (long)blockIdx.x * blockDim.x + threadIdx.x;  // total 4*64*512
  h16[idx] = (f16)h0[idx];
  c32[idx] = c0[idx];
}

// Persistent kernel: 8192 LSTM cells, one device-wide barrier per cell.
// 32 blocks x 512 threads (8 waves). Block owns 16 hidden cols (all 4 gates).
// Wave wid = kh*4+g: gate g, K-half kh. 64 MFMAs/wave/cell. Weights double-buffered
// in registers (B/Bn, 16 frags each), next cell prefetched after MFMA phase.
__global__ __launch_bounds__(512, 2) void lstm_persist(
    const f16* __restrict__ xt,
    const f16* __restrict__ wt_enc, const f16* __restrict__ wt_dec,
    const float* __restrict__ enc_b, const float* __restrict__ dec_b,
    f16* __restrict__ h_enc, f16* __restrict__ h_dec,
    float* __restrict__ c_enc, float* __restrict__ c_dec,
    f16* __restrict__ ys, int* __restrict__ ctr) {
  const int tid = threadIdx.x;
  const int lane = tid & 63;
  const int wid = tid >> 6;
  const int g = wid & 3;
  const int kh = wid >> 2;
  const int col = lane & 15;
  const int kg = lane >> 4;
  const int nt = blockIdx.x;
  const int n0 = nt << 4;

  __shared__ float zred[8][64][17];

  // this wave's weight slice: 8192 elements per (cell,nt,g,kh); lane offset lane*8
  const long wslice = ((long)(nt * 4 + g) * 2 + kh) * 8192 + lane * 8;
  const long wcellstride = (long)32 * 4 * 2 * 8192;  // 2^21 elements per cell

  f16x8 B[16], Bn[16];

  // prefetch weights for step 0 (encoder cell 0)
  {
    const f16* w = wt_enc + wslice;
#pragma unroll
    for (int kk = 0; kk < 16; ++kk) Bn[kk] = *(const f16x8*)(w + kk * 512);
  }

  const int HSz = BS * SH;

  for (int s = 0; s < NSTEP; ++s) {
#pragma unroll
    for (int kk = 0; kk < 16; ++kk) B[kk] = Bn[kk];

    // ---- schedule decode (uniform scalar) ----
    const bool enc = s < 4096;
    const int sp = enc ? s : s - 4096;
    const int v = sp >> 2, e = sp & 3, L = v & 3, t = v >> 2, p = v & 1;
    const f16* inp;
    if (enc) {
      inp = (e == 0) ? (xt + (long)t * HSz)
                     : (h_enc + ((1 - p) * 4 + (e - 1)) * HSz);
    } else {
      if (e == 0)
        inp = (v == 0) ? (h_enc + 3 * HSz)            // state0: enc buf0 slot3
                       : (h_dec + (p * 4 + 3) * HSz); // prev list's state
      else
        inp = h_dec + ((1 - p) * 4 + (e - 1)) * HSz;
    }
    const f16* hin = (enc ? h_enc : h_dec) + (p * 4 + e) * HSz;
    f16* hout = (enc ? h_enc : h_dec) + ((1 - p) * 4 + e) * HSz;
    float* cs = (enc ? c_enc : c_dec) + e * HSz;
    const float* bias = (enc ? enc_b : dec_b) + (L * 4 + e) * 2048;
    const int ysj = (!enc && e == 3) ? (t * 4 + L) : -1;

    // A source: kh=0 -> inp (k 0..511), kh=1 -> hin (k 512..1023)
    const f16* abase = ((kh == 0) ? inp : hin) + col * SH + kg * 8;

    f32x4 acc[4];
#pragma unroll
    for (int mi = 0; mi < 4; ++mi) acc[mi] = 0.f;

#pragma unroll
    for (int kk = 0; kk < 16; ++kk) {
      const f16* ab = abase + kk * 32;
      f16x8 a0 = *(const f16x8*)(ab + (0 * 16) * SH);
      f16x8 a1 = *(const f16x8*)(ab + (1 * 16) * SH);
      f16x8 a2 = *(const f16x8*)(ab + (2 * 16) * SH);
      f16x8 a3 = *(const f16x8*)(ab + (3 * 16) * SH);
      acc[0] = __builtin_amdgcn_mfma_f32_16x16x32_f16(a0, B[kk], acc[0], 0, 0, 0);
      acc[1] = __builtin_amdgcn_mfma_f32_16x16x32_f16(a1, B[kk], acc[1], 0, 0, 0);
      acc[2] = __builtin_amdgcn_mfma_f32_16x16x32_f16(a2, B[kk], acc[2], 0, 0, 0);
      acc[3] = __builtin_amdgcn_mfma_f32_16x16x32_f16(a3, B[kk], acc[3], 0, 0, 0);
    }

    // prefetch next step's weights (latency hides under zred/gate/barrier)
    if (s + 1 < NSTEP) {
      const int s2 = s + 1;
      const int sp2 = (s2 < 4096) ? s2 : s2 - 4096;
      const int e2 = sp2 & 3, L2 = (sp2 >> 2) & 3;
      const f16* w = ((s2 < 4096) ? wt_enc : wt_dec) +
                     (long)(L2 * 4 + e2) * wcellstride + wslice;
#pragma unroll
      for (int kk = 0; kk < 16; ++kk) Bn[kk] = *(const f16x8*)(w + kk * 512);
    }

    // ---- cross-wave K reduction via LDS ----
#pragma unroll
    for (int mi = 0; mi < 4; ++mi)
#pragma unroll
      for (int r = 0; r < 4; ++r)
        zred[wid][mi * 16 + kg * 4 + r][col] = acc[mi][r];

    __syncthreads();

    // ---- gate phase: two (row, col) items per thread ----
    {
      const int ci = tid & 15, n = n0 + ci;
      const float bf = bias[n], bi = bias[512 + n], bg = bias[1024 + n], bo = bias[1536 + n];
#pragma unroll
      for (int rr = 0; rr < 2; ++rr) {
        const int row = (tid >> 4) * 2 + rr;
        float zf = bf + zred[0][row][ci] + zred[4][row][ci];
        float zi = bi + zred[1][row][ci] + zred[5][row][ci];
        float zg = bg + zred[2][row][ci] + zred[6][row][ci];
        float zo = bo + zred[3][row][ci] + zred[7][row][ci];
        float f = sigmoidf_(zf);
        float i = sigmoidf_(zi);
        float gg = tanhf_(zg);
        float o = sigmoidf_(zo);
        float cc = f * cs[row * SH + n] + i * gg;
        cs[row * SH + n] = cc;
        f16 h = (f16)(o * tanhf_(cc));
        hout[row * SH + n] = h;
        if (ysj >= 0) ys[((long)row * 1024 + ysj) * SH + n] = h;
      }
    }

    // ---- device-wide barrier (leader-based, monotone counter) ----
    __syncthreads();  // drains all waves' stores before leader signals
    if (tid == 0) {
      __threadfence();
      __hip_atomic_fetch_add(ctr, 1, __ATOMIC_RELEASE, __HIP_MEMORY_SCOPE_AGENT);
      const int target = (s + 1) * NB;
      while (__hip_atomic_load(ctr, __ATOMIC_ACQUIRE, __HIP_MEMORY_SCOPE_AGENT) < target)
        __builtin_amdgcn_s_sleep(2);
    }
    __syncthreads();
  }
}

// out[m][n] = sigmoid( ys[m][:] @ fint[n][:] + fin_b[n] )
__global__ __launch_bounds__(256) void final_gemm(const f16* __restrict__ ys,
                                                  const f16* __restrict__ fint,
                                                  const float* __restrict__ finb,
                                                  float* __restrict__ out) {
  const int lane = threadIdx.x & 63;
  const int w = threadIdx.x >> 6;
  const int col = lane & 15;
  const int kg = lane >> 4;
  const long m0 = (long)blockIdx.y * 64;
  const int n0 = (blockIdx.x * 4 + w) * 16;

  f32x4 acc[4];
#pragma unroll
  for (int mi = 0; mi < 4; ++mi) acc[mi] = 0.f;

#pragma unroll 2
  for (int kk = 0; kk < 16; ++kk) {
    f16x8 b = *(const f16x8*)(fint + (long)(n0 + col) * 512 + kk * 32 + kg * 8);
#pragma unroll
    for (int mi = 0; mi < 4; ++mi) {
      f16x8 a = *(const f16x8*)(ys + (m0 + mi * 16 + col) * 512 + kk * 32 + kg * 8);
      acc[mi] = __builtin_amdgcn_mfma_f32_16x16x32_f16(a, b, acc[mi], 0, 0, 0);
    }
  }
  const int n = n0 + col;
  const float bn = finb[n];
#pragma unroll
  for (int mi = 0; mi < 4; ++mi)
#pragma unroll
    for (int r = 0; r < 4; ++r)
      out[(m0 + mi * 16 + kg * 4 + r) * 512 + n] = sigmoidf_(acc[mi][r] + bn);
}

extern "C" void kernel_launch(void* const* d_in, const int* in_sizes, int n_in,
                              void* d_out, int out_size, void* d_ws, size_t ws_size,
                              hipStream_t stream) {
  const float* x      = (const float*)d_in[0];
  const float* enc_W  = (const float*)d_in[2];
  const float* enc_V  = (const float*)d_in[3];
  const float* enc_b  = (const float*)d_in[4];
  const float* enc_h0 = (const float*)d_in[5];
  const float* enc_c0 = (const float*)d_in[6];
  const float* dec_W  = (const float*)d_in[7];
  const float* dec_V  = (const float*)d_in[8];
  const float* dec_b  = (const float*)d_in[9];
  const float* dec_h0 = (const float*)d_in[10];
  const float* dec_c0 = (const float*)d_in[11];
  const float* fin_W  = (const float*)d_in[12];
  const float* fin_b  = (const float*)d_in[13];
  float* out = (float*)d_out;

  // workspace layout
  f16* wt_enc = (f16*)d_ws;                                   // 16*2048*1024
  f16* wt_dec = wt_enc + (long)16 * 2048 * 1024;              // 16*2048*1024
  f16* xt     = wt_dec + (long)16 * 2048 * 1024;              // 256*64*512
  f16* fint   = xt + (long)SL * BS * SI;                      // 512*512
  f16* ys     = fint + (long)SH * SI;                         // 64*1024*512
  f16* h_enc  = ys + (long)BS * (FL * 4) * SH;                // 2*4*64*512
  f16* h_dec  = h_enc + (long)2 * 4 * BS * SH;                // 2*4*64*512
  float* c_enc = (float*)(h_dec + (long)2 * 4 * BS * SH);     // 4*64*512 f32
  float* c_dec = c_enc + (long)4 * BS * SH;                   // 4*64*512 f32
  int* ctr = (int*)(c_dec + (long)4 * BS * SH);

  hipMemsetAsync(ctr, 0, 256, stream);

  conv_w<<<131072, 256, 0, stream>>>(enc_W, enc_V, wt_enc);
  conv_w<<<131072, 256, 0, stream>>>(dec_W, dec_V, wt_dec);
  conv_x<<<32768, 256, 0, stream>>>(x, xt);
  conv_fin<<<1024, 256, 0, stream>>>(fin_W, fint);
  init_state<<<512, 256, 0, stream>>>(enc_h0, enc_c0, h_enc, c_enc);
  init_state<<<512, 256, 0, stream>>>(dec_h0, dec_c0, h_dec, c_dec);

  lstm_persist<<<NB, 512, 0, stream>>>(xt, wt_enc, wt_dec, enc_b, dec_b,
                                       h_enc, h_dec, c_enc, c_dec, ys, ctr);

  dim3 fg(8, 1024);
  final_gemm<<<fg, 256, 0, stream>>>(ys, fint, fin_b, out);
}